// Round 1
// baseline (435.247 us; speedup 1.0000x reference)
//
#include <hip/hip_runtime.h>
#include <math.h>

#define C_C   0.01f
#define SQC   0.1f          // sqrt(c)
#define EPSF  1e-15f
#define TCLIP (1.0f - 1e-6f)

__device__ __forceinline__ float wred(float v) {
#pragma unroll
    for (int off = 32; off > 0; off >>= 1) v += __shfl_xor(v, off, 64);
    return v;
}

__device__ __forceinline__ float dot4(const float4& a, const float4& b) {
    return a.x * b.x + a.y * b.y + a.z * b.z + a.w * b.w;
}

// ---------------------------------------------------------------------------
// Kernel 1: build the 128 queries (log-map -> Givens rotation -> exp-map ->
// mobius_add with exp-map(rel_trans)). One 64-lane wave per query; each lane
// owns elements [4*lane, 4*lane+4) and [256+4*lane, 256+4*lane+4) of D=512.
// Pairs (2i, 2i+1) are lane-local in this layout.
// ---------------------------------------------------------------------------
__global__ __launch_bounds__(64)
void build_queries(const float* __restrict__ ent,
                   const float* __restrict__ rrot,
                   const float* __restrict__ rtrans,
                   const float* __restrict__ ebias,
                   const int* __restrict__ trip,
                   float* __restrict__ qbuf,   // [B][512]
                   float* __restrict__ q2buf,  // [B]
                   float* __restrict__ sbbuf)  // [B]
{
    const int b    = blockIdx.x;
    const int lane = threadIdx.x;
    const int t0   = trip[b * 3 + 0];
    const int r    = trip[b * 3 + 1];

    const float* srow = ent + (size_t)t0 * 512;
    float4 s0 = *(const float4*)(srow + 4 * lane);
    float4 s1 = *(const float4*)(srow + 256 + 4 * lane);

    // log_map_zero
    float ss = dot4(s0, s0) + dot4(s1, s1);
    ss = wred(ss);
    float yn  = fmaxf(sqrtf(ss), EPSF);
    float arg = fminf(SQC * yn, TCLIP);
    float fl  = atanhf(arg) / (SQC * yn);

    // givens rotation on s_tan = fl * s
    const float* arow = rrot + (size_t)r * 256;
    float2 a01 = *(const float2*)(arow + 2 * lane);
    float2 a23 = *(const float2*)(arow + 128 + 2 * lane);
    float c0, n0, c1, n1, c2, n2, c3, n3;
    sincosf(a01.x, &n0, &c0);
    sincosf(a01.y, &n1, &c1);
    sincosf(a23.x, &n2, &c2);
    sincosf(a23.y, &n3, &c3);

    float t0x = s0.x * fl, t0y = s0.y * fl, t0z = s0.z * fl, t0w = s0.w * fl;
    float t1x = s1.x * fl, t1y = s1.y * fl, t1z = s1.z * fl, t1w = s1.w * fl;

    float4 r0, r1;
    r0.x = c0 * t0x - n0 * t0y;  r0.y = n0 * t0x + c0 * t0y;
    r0.z = c1 * t0z - n1 * t0w;  r0.w = n1 * t0z + c1 * t0w;
    r1.x = c2 * t1x - n2 * t1y;  r1.y = n2 * t1x + c2 * t1y;
    r1.z = c3 * t1z - n3 * t1w;  r1.w = n3 * t1z + c3 * t1w;

    // exp_map_zero(rot)
    float vv = dot4(r0, r0) + dot4(r1, r1);
    vv = wred(vv);
    float vn = fmaxf(sqrtf(vv), EPSF);
    float fx = tanhf(SQC * vn) / (SQC * vn);

    // exp_map_zero(rel_trans)
    const float* trow = rtrans + (size_t)r * 512;
    float4 u0 = *(const float4*)(trow + 4 * lane);
    float4 u1 = *(const float4*)(trow + 256 + 4 * lane);
    float tt = dot4(u0, u0) + dot4(u1, u1);
    float rt = dot4(r0, u0) + dot4(r1, u1);
    tt = wred(tt);
    rt = wred(rt);
    float tn = fmaxf(sqrtf(tt), EPSF);
    float fy = tanhf(SQC * tn) / (SQC * tn);

    // mobius_add(x = fx*rot, y = fy*trans)
    float x2 = fx * fx * vv;
    float y2 = fy * fy * tt;
    float xy = fx * fy * rt;
    float ca  = 1.0f + 2.0f * C_C * xy + C_C * y2;
    float cb  = 1.0f - C_C * x2;
    float den = fmaxf(1.0f + 2.0f * C_C * xy + C_C * C_C * x2 * y2, EPSF);
    float inv = 1.0f / den;

    float4 q0, q1;
    q0.x = (ca * fx * r0.x + cb * fy * u0.x) * inv;
    q0.y = (ca * fx * r0.y + cb * fy * u0.y) * inv;
    q0.z = (ca * fx * r0.z + cb * fy * u0.z) * inv;
    q0.w = (ca * fx * r0.w + cb * fy * u0.w) * inv;
    q1.x = (ca * fx * r1.x + cb * fy * u1.x) * inv;
    q1.y = (ca * fx * r1.y + cb * fy * u1.y) * inv;
    q1.z = (ca * fx * r1.z + cb * fy * u1.z) * inv;
    q1.w = (ca * fx * r1.w + cb * fy * u1.w) * inv;

    float qq = dot4(q0, q0) + dot4(q1, q1);
    qq = wred(qq);

    float* qrow = qbuf + (size_t)b * 512;
    *(float4*)(qrow + 4 * lane)       = q0;
    *(float4*)(qrow + 256 + 4 * lane) = q1;
    if (lane == 0) {
        q2buf[b] = qq;
        sbbuf[b] = ebias[t0];
    }
}

// ---------------------------------------------------------------------------
// Kernel 2: scores[b][e] = -dist(q_b, ent_e) + ebias[e] + sb[b].
// dist via expanded mobius form needs only dot(q,e), q2, e2.
// Tiling: block = 128 queries (all) x 128 entities, K-steps of 32.
// 256 threads as 16x16; thread tile 8 q x 8 e. LDS f4 slots XOR-swizzled by
// (row>>3)&7 so ds_read_b128 is conflict-free (q: 4-way broadcast, e: 2-way).
// ---------------------------------------------------------------------------
__global__ __launch_bounds__(256)
void score_k(const float* __restrict__ ent,
             const float* __restrict__ ebias,
             const float* __restrict__ qbuf,
             const float* __restrict__ q2buf,
             const float* __restrict__ sbbuf,
             float* __restrict__ out, int E)
{
    __shared__ float qs[128 * 32];
    __shared__ float es[128 * 32];

    const int tid = threadIdx.x;
    const int tx  = tid & 15;
    const int ty  = tid >> 4;
    const int e0  = blockIdx.x * 128;

    float acc[8][8];
    float e2a[8];
#pragma unroll
    for (int i = 0; i < 8; ++i) {
        e2a[i] = 0.0f;
#pragma unroll
        for (int j = 0; j < 8; ++j) acc[i][j] = 0.0f;
    }

    for (int k0 = 0; k0 < 512; k0 += 32) {
        __syncthreads();
#pragma unroll
        for (int i = 0; i < 4; ++i) {
            int idx = i * 256 + tid;          // 0..1023
            int row = idx >> 3;               // 0..127
            int c4  = idx & 7;                // f4 column within K-slab
            int sw  = (c4 ^ ((row >> 3) & 7)) << 2;
            float4 v = *(const float4*)(qbuf + (size_t)row * 512 + k0 + c4 * 4);
            *(float4*)(qs + row * 32 + sw) = v;
            float4 w = *(const float4*)(ent + (size_t)(e0 + row) * 512 + k0 + c4 * 4);
            *(float4*)(es + row * 32 + sw) = w;
        }
        __syncthreads();

#pragma unroll
        for (int c4 = 0; c4 < 8; ++c4) {
            float4 ev[8];
#pragma unroll
            for (int j = 0; j < 8; ++j) {
                int row = tx * 8 + j;
                ev[j] = *(const float4*)(es + row * 32 + ((c4 ^ ((row >> 3) & 7)) << 2));
                e2a[j] += dot4(ev[j], ev[j]);
            }
#pragma unroll
            for (int i = 0; i < 8; ++i) {
                int row = ty * 8 + i;
                float4 qv = *(const float4*)(qs + row * 32 + ((c4 ^ ((row >> 3) & 7)) << 2));
#pragma unroll
                for (int j = 0; j < 8; ++j)
                    acc[i][j] += dot4(qv, ev[j]);
            }
        }
    }

    float be[8];
#pragma unroll
    for (int j = 0; j < 8; ++j) be[j] = ebias[e0 + tx * 8 + j];

#pragma unroll
    for (int i = 0; i < 8; ++i) {
        const int q  = ty * 8 + i;
        const float q2 = q2buf[q];
        const float sb = sbbuf[q];
        const float cb = 1.0f - C_C * q2;
        float res[8];
#pragma unroll
        for (int j = 0; j < 8; ++j) {
            float xy  = -acc[i][j];
            float e2  = e2a[j];
            float ca  = 1.0f + 2.0f * C_C * xy + C_C * e2;
            float den = fmaxf(1.0f + 2.0f * C_C * xy + C_C * C_C * q2 * e2, EPSF);
            float id2 = 1.0f / (den * den);
            float dist = (ca * ca * q2 + 2.0f * ca * cb * xy + cb * cb * e2) * id2;
            res[j] = sb + be[j] - dist;
        }
        float* orow = out + (size_t)q * E + e0 + tx * 8;
        *(float4*)(orow)     = make_float4(res[0], res[1], res[2], res[3]);
        *(float4*)(orow + 4) = make_float4(res[4], res[5], res[6], res[7]);
    }
}

extern "C" void kernel_launch(void* const* d_in, const int* in_sizes, int n_in,
                              void* d_out, int out_size, void* d_ws, size_t ws_size,
                              hipStream_t stream) {
    const float* ent    = (const float*)d_in[0];
    // d_in[1] = rel_embedding: unused by the reference
    const float* rrot   = (const float*)d_in[2];
    const float* rtrans = (const float*)d_in[3];
    const float* ebias  = (const float*)d_in[4];
    const int*   trip   = (const int*)d_in[5];
    float* out = (float*)d_out;

    const int B = in_sizes[5] / 3;    // 128
    const int E = in_sizes[0] / 512;  // 40960

    float* qbuf  = (float*)d_ws;            // B*512 floats
    float* q2buf = qbuf + (size_t)B * 512;  // B floats
    float* sbbuf = q2buf + B;               // B floats

    build_queries<<<B, 64, 0, stream>>>(ent, rrot, rtrans, ebias, trip,
                                        qbuf, q2buf, sbbuf);
    score_k<<<E / 128, 256, 0, stream>>>(ent, ebias, qbuf, q2buf, sbbuf, out, E);
}

// Round 2
// 145.463 us; speedup vs baseline: 2.9921x; 2.9921x over previous
//
#include <hip/hip_runtime.h>
#include <math.h>

#define C_C   0.01f
#define SQC   0.1f          // sqrt(c)
#define EPSF  1e-15f
#define TCLIP (1.0f - 1e-6f)

typedef short short8 __attribute__((ext_vector_type(8)));
typedef float f32x4  __attribute__((ext_vector_type(4)));

__device__ __forceinline__ float wred(float v) {
#pragma unroll
    for (int off = 32; off > 0; off >>= 1) v += __shfl_xor(v, off, 64);
    return v;
}

__device__ __forceinline__ float dot4(const float4& a, const float4& b) {
    return a.x * b.x + a.y * b.y + a.z * b.z + a.w * b.w;
}

// fp32 -> bf16 with round-nearest-even, as raw ushort bits
__device__ __forceinline__ unsigned int f2bf(float f) {
    unsigned int u = __float_as_uint(f);
    u += 0x7fffu + ((u >> 16) & 1u);
    return u >> 16;
}
__device__ __forceinline__ unsigned int pk2(float a, float b) {
    return f2bf(a) | (f2bf(b) << 16);
}

// ---------------------------------------------------------------------------
// Kernel 1: build the 128 queries; emit them as bf16 rows for the MFMA GEMM,
// plus fp32 q2 (squared norm, pre-rounding) and subject bias.
// One wave per query; lane owns elems [4L,4L+4) and [256+4L,256+4L+4).
// ---------------------------------------------------------------------------
__global__ __launch_bounds__(64)
void build_queries(const float* __restrict__ ent,
                   const float* __restrict__ rrot,
                   const float* __restrict__ rtrans,
                   const float* __restrict__ ebias,
                   const int* __restrict__ trip,
                   unsigned short* __restrict__ qb,  // [B][512] bf16 bits
                   float* __restrict__ q2buf,        // [B]
                   float* __restrict__ sbbuf)        // [B]
{
    const int b    = blockIdx.x;
    const int lane = threadIdx.x;
    const int t0   = trip[b * 3 + 0];
    const int r    = trip[b * 3 + 1];

    const float* srow = ent + (size_t)t0 * 512;
    float4 s0 = *(const float4*)(srow + 4 * lane);
    float4 s1 = *(const float4*)(srow + 256 + 4 * lane);

    // log_map_zero
    float ss = dot4(s0, s0) + dot4(s1, s1);
    ss = wred(ss);
    float yn  = fmaxf(sqrtf(ss), EPSF);
    float arg = fminf(SQC * yn, TCLIP);
    float fl  = atanhf(arg) / (SQC * yn);

    // givens rotation on s_tan = fl * s
    const float* arow = rrot + (size_t)r * 256;
    float2 a01 = *(const float2*)(arow + 2 * lane);
    float2 a23 = *(const float2*)(arow + 128 + 2 * lane);
    float c0, n0, c1, n1, c2, n2, c3, n3;
    sincosf(a01.x, &n0, &c0);
    sincosf(a01.y, &n1, &c1);
    sincosf(a23.x, &n2, &c2);
    sincosf(a23.y, &n3, &c3);

    float t0x = s0.x * fl, t0y = s0.y * fl, t0z = s0.z * fl, t0w = s0.w * fl;
    float t1x = s1.x * fl, t1y = s1.y * fl, t1z = s1.z * fl, t1w = s1.w * fl;

    float4 r0, r1;
    r0.x = c0 * t0x - n0 * t0y;  r0.y = n0 * t0x + c0 * t0y;
    r0.z = c1 * t0z - n1 * t0w;  r0.w = n1 * t0z + c1 * t0w;
    r1.x = c2 * t1x - n2 * t1y;  r1.y = n2 * t1x + c2 * t1y;
    r1.z = c3 * t1z - n3 * t1w;  r1.w = n3 * t1z + c3 * t1w;

    // exp_map_zero(rot)
    float vv = dot4(r0, r0) + dot4(r1, r1);
    vv = wred(vv);
    float vn = fmaxf(sqrtf(vv), EPSF);
    float fx = tanhf(SQC * vn) / (SQC * vn);

    // exp_map_zero(rel_trans)
    const float* trow = rtrans + (size_t)r * 512;
    float4 u0 = *(const float4*)(trow + 4 * lane);
    float4 u1 = *(const float4*)(trow + 256 + 4 * lane);
    float tt = dot4(u0, u0) + dot4(u1, u1);
    float rt = dot4(r0, u0) + dot4(r1, u1);
    tt = wred(tt);
    rt = wred(rt);
    float tn = fmaxf(sqrtf(tt), EPSF);
    float fy = tanhf(SQC * tn) / (SQC * tn);

    // mobius_add(x = fx*rot, y = fy*trans)
    float x2 = fx * fx * vv;
    float y2 = fy * fy * tt;
    float xy = fx * fy * rt;
    float ca  = 1.0f + 2.0f * C_C * xy + C_C * y2;
    float cb  = 1.0f - C_C * x2;
    float den = fmaxf(1.0f + 2.0f * C_C * xy + C_C * C_C * x2 * y2, EPSF);
    float inv = 1.0f / den;

    float4 q0, q1;
    q0.x = (ca * fx * r0.x + cb * fy * u0.x) * inv;
    q0.y = (ca * fx * r0.y + cb * fy * u0.y) * inv;
    q0.z = (ca * fx * r0.z + cb * fy * u0.z) * inv;
    q0.w = (ca * fx * r0.w + cb * fy * u0.w) * inv;
    q1.x = (ca * fx * r1.x + cb * fy * u1.x) * inv;
    q1.y = (ca * fx * r1.y + cb * fy * u1.y) * inv;
    q1.z = (ca * fx * r1.z + cb * fy * u1.z) * inv;
    q1.w = (ca * fx * r1.w + cb * fy * u1.w) * inv;

    float qq = dot4(q0, q0) + dot4(q1, q1);
    qq = wred(qq);

    unsigned short* qrow = qb + (size_t)b * 512;
    uint2 h0, h1;
    h0.x = pk2(q0.x, q0.y);  h0.y = pk2(q0.z, q0.w);
    h1.x = pk2(q1.x, q1.y);  h1.y = pk2(q1.z, q1.w);
    *(uint2*)(qrow + 4 * lane)       = h0;
    *(uint2*)(qrow + 256 + 4 * lane) = h1;
    if (lane == 0) {
        q2buf[b] = qq;
        sbbuf[b] = ebias[t0];
    }
}

// ---------------------------------------------------------------------------
// Kernel 2: bf16-MFMA scoring. Block = 128 q x 64 e, 4 waves (2x2), wave tile
// 64x32 via mfma_f32_16x16x32_bf16 (frags: A row=l&15,k=(l>>4)*8+j; same for
// B; C/D col=l&15,row=(l>>4)*4+reg). BK=64. Entity tile reg-staged with
// fp32->bf16 pack; e2 accumulated in fp32 from the same loads. All LDS 16B
// slots XOR-swizzled by (row&7)<<4 -> conflict-free b128 writes and reads.
// ---------------------------------------------------------------------------
__global__ __launch_bounds__(256)
void score_mfma(const float* __restrict__ ent,
                const float* __restrict__ ebias,
                const unsigned short* __restrict__ qb,
                const float* __restrict__ q2buf,
                const float* __restrict__ sbbuf,
                float* __restrict__ out, int E)
{
    __shared__ unsigned short qs[128 * 64];  // 16 KB
    __shared__ unsigned short es[64 * 64];   // 8 KB
    __shared__ float e2s[64];

    const int tid  = threadIdx.x;
    const int lane = tid & 63;
    const int wid  = tid >> 6;   // 0..3
    const int wr   = wid >> 1;   // M half (64 rows)
    const int wc   = wid & 1;    // N half (32 cols)
    const int e0   = blockIdx.x * 64;

    f32x4 acc[4][2];
#pragma unroll
    for (int mi = 0; mi < 4; ++mi)
#pragma unroll
        for (int nj = 0; nj < 2; ++nj) acc[mi][nj] = (f32x4)0.0f;

    // entity rows this thread stages (constant across K-tiles)
    const int erow0 = tid >> 3;          // 0..31
    const int ekc   = tid & 7;
    float e2p0 = 0.0f, e2p1 = 0.0f;

    for (int k0 = 0; k0 < 512; k0 += 64) {
        __syncthreads();
        // ---- stage Q tile: 1024 x 16B chunks, 4 per thread (bf16 copy)
#pragma unroll
        for (int i = 0; i < 4; ++i) {
            int ci  = i * 256 + tid;
            int row = ci >> 3, kc = ci & 7;
            uint4 v = *(const uint4*)(qb + (size_t)row * 512 + k0 + kc * 8);
            int off = row * 128 + ((kc * 16) ^ ((row & 7) << 4));
            *(uint4*)((char*)qs + off) = v;
        }
        // ---- stage E tile: 512 chunks, 2 per thread, fp32->bf16 + e2
        {
            const float* src = ent + (size_t)(e0 + erow0) * 512 + k0 + ekc * 8;
            float4 f0 = *(const float4*)(src);
            float4 f1 = *(const float4*)(src + 4);
            e2p0 += dot4(f0, f0) + dot4(f1, f1);
            uint4 p = { pk2(f0.x, f0.y), pk2(f0.z, f0.w),
                        pk2(f1.x, f1.y), pk2(f1.z, f1.w) };
            int off = erow0 * 128 + ((ekc * 16) ^ ((erow0 & 7) << 4));
            *(uint4*)((char*)es + off) = p;
        }
        {
            int row = erow0 + 32;
            const float* src = ent + (size_t)(e0 + row) * 512 + k0 + ekc * 8;
            float4 f0 = *(const float4*)(src);
            float4 f1 = *(const float4*)(src + 4);
            e2p1 += dot4(f0, f0) + dot4(f1, f1);
            uint4 p = { pk2(f0.x, f0.y), pk2(f0.z, f0.w),
                        pk2(f1.x, f1.y), pk2(f1.z, f1.w) };
            int off = row * 128 + ((ekc * 16) ^ ((row & 7) << 4));
            *(uint4*)((char*)es + off) = p;
        }
        __syncthreads();

        // ---- compute: 2 MFMA K-steps of 32
#pragma unroll
        for (int ks = 0; ks < 2; ++ks) {
            const int kb = (ks * 32 + (lane >> 4) * 8) * 2;  // byte offset in row
            short8 a[4], bfr[2];
#pragma unroll
            for (int mi = 0; mi < 4; ++mi) {
                int row = wr * 64 + mi * 16 + (lane & 15);
                a[mi] = *(const short8*)((const char*)qs +
                         row * 128 + (kb ^ ((row & 7) << 4)));
            }
#pragma unroll
            for (int nj = 0; nj < 2; ++nj) {
                int row = wc * 32 + nj * 16 + (lane & 15);
                bfr[nj] = *(const short8*)((const char*)es +
                           row * 128 + (kb ^ ((row & 7) << 4)));
            }
#pragma unroll
            for (int mi = 0; mi < 4; ++mi)
#pragma unroll
                for (int nj = 0; nj < 2; ++nj)
                    acc[mi][nj] = __builtin_amdgcn_mfma_f32_16x16x32_bf16(
                        a[mi], bfr[nj], acc[mi][nj], 0, 0, 0);
        }
    }

    // ---- e2 reduction: 8 consecutive threads share one entity row
    e2p0 += __shfl_xor(e2p0, 1, 64);
    e2p0 += __shfl_xor(e2p0, 2, 64);
    e2p0 += __shfl_xor(e2p0, 4, 64);
    e2p1 += __shfl_xor(e2p1, 1, 64);
    e2p1 += __shfl_xor(e2p1, 2, 64);
    e2p1 += __shfl_xor(e2p1, 4, 64);
    if ((tid & 7) == 0) {
        e2s[erow0]      = e2p0;
        e2s[erow0 + 32] = e2p1;
    }
    __syncthreads();

    // ---- epilogue: closed-form mobius distance
    float e2v[2], bev[2];
#pragma unroll
    for (int nj = 0; nj < 2; ++nj) {
        int ecol = wc * 32 + nj * 16 + (lane & 15);
        e2v[nj] = e2s[ecol];
        bev[nj] = ebias[e0 + ecol];
    }
#pragma unroll
    for (int mi = 0; mi < 4; ++mi) {
        const int qbase = wr * 64 + mi * 16 + (lane >> 4) * 4;
        float q2a[4], sba[4];
#pragma unroll
        for (int r = 0; r < 4; ++r) {
            q2a[r] = q2buf[qbase + r];
            sba[r] = sbbuf[qbase + r];
        }
#pragma unroll
        for (int nj = 0; nj < 2; ++nj) {
            const int ecol = e0 + wc * 32 + nj * 16 + (lane & 15);
            const float e2 = e2v[nj];
            const float be = bev[nj];
#pragma unroll
            for (int r = 0; r < 4; ++r) {
                float q2  = q2a[r];
                float xy  = -acc[mi][nj][r];
                float ca  = 1.0f + 2.0f * C_C * xy + C_C * e2;
                float cb  = 1.0f - C_C * q2;
                float den = fmaxf(1.0f + 2.0f * C_C * xy + C_C * C_C * q2 * e2, EPSF);
                float id2 = 1.0f / (den * den);
                float dist = (ca * ca * q2 + 2.0f * ca * cb * xy + cb * cb * e2) * id2;
                out[(size_t)(qbase + r) * E + ecol] = sba[r] + be - dist;
            }
        }
    }
}

extern "C" void kernel_launch(void* const* d_in, const int* in_sizes, int n_in,
                              void* d_out, int out_size, void* d_ws, size_t ws_size,
                              hipStream_t stream) {
    const float* ent    = (const float*)d_in[0];
    // d_in[1] = rel_embedding: unused by the reference
    const float* rrot   = (const float*)d_in[2];
    const float* rtrans = (const float*)d_in[3];
    const float* ebias  = (const float*)d_in[4];
    const int*   trip   = (const int*)d_in[5];
    float* out = (float*)d_out;

    const int B = in_sizes[5] / 3;    // 128
    const int E = in_sizes[0] / 512;  // 40960

    unsigned short* qb = (unsigned short*)d_ws;          // B*512 bf16
    float* q2buf = (float*)(qb + (size_t)B * 512);       // B floats
    float* sbbuf = q2buf + B;                            // B floats

    build_queries<<<B, 64, 0, stream>>>(ent, rrot, rtrans, ebias, trip,
                                        qb, q2buf, sbbuf);
    score_mfma<<<E / 64, 256, 0, stream>>>(ent, ebias, qb, q2buf, sbbuf, out, E);
}